// Round 2
// baseline (166.592 us; speedup 1.0000x reference)
//
#include <hip/hip_runtime.h>

#define SEQ 512
#define HID 768
#define P2  46
#define MT  64          // rows per block (4 waves x 16 rows)
#define BLK 256
#define NSTEP (HID / 32)   // 24 MFMA K-steps
#define WROWS 48           // padded W rows in LDS (reads of 46/47 are junk, masked at store)

typedef short bf16x8 __attribute__((ext_vector_type(8)));
typedef float f32x4  __attribute__((ext_vector_type(4)));

__device__ __forceinline__ unsigned short f2bf(float f) {
  union { float f; unsigned int u; } v; v.f = f;
  return (unsigned short)((v.u + 0x7FFFu + ((v.u >> 16) & 1u)) >> 16);
}

// Fused, barrier-free K-loop:
//   A: global -> regs (each wave owns 16 rows exclusively, 4-deep prefetch)
//   B: W staged ONCE per block as bf16 in LDS, 16B-chunk XOR swizzle (conflict-free)
//   q[b,:]: per-block redundant fp32 dots (prologue, overlapped with W staging)
__global__ __launch_bounds__(BLK, 2) void fused_kernel(
    const float* __restrict__ h, const int* __restrict__ ids,
    const int* __restrict__ mask, const float* __restrict__ W,
    const float* __restrict__ bias, float* __restrict__ out) {

  // [48 rows][96 chunks of 16B]; chunk c stored at c' = (c&~7)|((c^p)&7)
  __shared__ __align__(16) unsigned short wB[WROWS][HID];   // 73728 B
  __shared__ float q_s[P2];

  const int tid  = threadIdx.x;
  const int lane = tid & 63, wv = tid >> 6;     // 4 waves
  const int mr = lane & 15, qd = lane >> 4;
  const int row0 = blockIdx.x * MT;             // flat row = b*SEQ + s
  const int b    = row0 >> 9;                   // SEQ = 512

  // ---- stage W once: fp32 global -> bf16 LDS, swizzled (46*192 float4) ----
  #pragma unroll
  for (int i = 0; i < 35; ++i) {
    int idx = tid + i * BLK;                    // float4 index
    if (idx < P2 * 192) {
      int p  = idx / 192;
      int c4 = idx - p * 192;                   // float4 within row
      float4 v = *(const float4*)(W + (size_t)p * HID + (c4 << 2));
      ushort4 u;
      u.x = f2bf(v.x); u.y = f2bf(v.y); u.z = f2bf(v.z); u.w = f2bf(v.w);
      int c  = c4 >> 1;                         // 16B chunk 0..95
      int cs = (c & 0x78) | ((c ^ p) & 7);
      *(ushort4*)&wB[p][(cs << 3) + ((c4 & 1) << 2)] = u;
    }
  }

  // ---- q[b,p] = (h[b,i0,:]+h[b,i1,:]) . W[p,:]  (fp32, wave-parallel) ----
  {
    const int i0 = ids[b * 2 + 0], i1 = ids[b * 2 + 1];
    const float* r0p = h + ((size_t)b * SEQ + i0) * HID;
    const float* r1p = h + ((size_t)b * SEQ + i1) * HID;
    for (int p = wv; p < P2; p += 4) {
      const float* wp = W + (size_t)p * HID;
      float a = 0.f;
      #pragma unroll
      for (int j = 0; j < HID / 64; ++j) {
        int k = lane + (j << 6);
        a += (r0p[k] + r1p[k]) * wp[k];
      }
      #pragma unroll
      for (int off = 32; off > 0; off >>= 1) a += __shfl_xor(a, off, 64);
      if (lane == 0) q_s[p] = a;
    }
  }

  // ---- A-stream prologue: 4-deep register prefetch (no LDS, no barriers) ----
  const int arow = row0 + (wv << 4) + mr;       // this lane's h row
  const float* abase = h + (size_t)arow * HID + (qd << 3);
  float4 pa[4][2];
  #pragma unroll
  for (int s = 0; s < 4; ++s) {
    pa[s][0] = *(const float4*)(abase + (s << 5));
    pa[s][1] = *(const float4*)(abase + (s << 5) + 4);
  }

  __syncthreads();   // W + q_s visible; A prefetch drains harmlessly

  f32x4 acc[3];
  #pragma unroll
  for (int nt = 0; nt < 3; ++nt) acc[nt] = f32x4{0.f, 0.f, 0.f, 0.f};

  // ---- main loop: 24 steps, fully unrolled, register-rotated prefetch ----
  #pragma unroll
  for (int s = 0; s < NSTEP; ++s) {
    float4 c0 = pa[s & 3][0], c1 = pa[s & 3][1];
    if (s + 4 < NSTEP) {
      pa[s & 3][0] = *(const float4*)(abase + ((s + 4) << 5));
      pa[s & 3][1] = *(const float4*)(abase + ((s + 4) << 5) + 4);
    }
    bf16x8 a = { (short)f2bf(c0.x), (short)f2bf(c0.y),
                 (short)f2bf(c0.z), (short)f2bf(c0.w),
                 (short)f2bf(c1.x), (short)f2bf(c1.y),
                 (short)f2bf(c1.z), (short)f2bf(c1.w) };
    int c  = (s << 2) + qd;                     // 16B chunk index
    int cs = (c & 0x78) | ((c ^ mr) & 7);       // p&7 == mr&7 for all nt
    #pragma unroll
    for (int nt = 0; nt < 3; ++nt) {
      bf16x8 bb = *(const bf16x8*)&wB[(nt << 4) + mr][cs << 3];
      acc[nt] = __builtin_amdgcn_mfma_f32_16x16x32_bf16(a, bb, acc[nt], 0, 0, 0);
    }
  }

  // ---- epilogue: C/D col = mr, row = qd*4 + i ----
  const int rbase = row0 + (wv << 4) + (qd << 2);
  int msk[4];
  #pragma unroll
  for (int i = 0; i < 4; ++i) msk[i] = mask[rbase + i];

  #pragma unroll
  for (int nt = 0; nt < 3; ++nt) {
    int p = (nt << 4) + mr;
    if (p < P2) {
      float bv = bias[p], qv = q_s[p];
      #pragma unroll
      for (int i = 0; i < 4; ++i) {
        float x = acc[nt][i] + bv + (msk[i] ? qv : 0.f);
        float sg = 1.f / (1.f + __expf(-x));
        sg *= sg; sg *= sg;               // sigmoid^4
        out[(size_t)(rbase + i) * P2 + p] = sg;
      }
    }
  }
}

extern "C" void kernel_launch(void* const* d_in, const int* in_sizes, int n_in,
                              void* d_out, int out_size, void* d_ws, size_t ws_size,
                              hipStream_t stream) {
  const float* h    = (const float*)d_in[0];   // [64,512,768] fp32
  const int*   ids  = (const int*)d_in[1];     // [64,2]
  const int*   mask = (const int*)d_in[2];     // [64,512]
  const float* W    = (const float*)d_in[3];   // [46,768]
  const float* bias = (const float*)d_in[4];   // [46]
  float* out = (float*)d_out;                  // [64,512,46] fp32

  fused_kernel<<<dim3((64 * SEQ) / MT), BLK, 0, stream>>>(h, ids, mask, W, bias, out);
}

// Round 3
// 166.069 us; speedup vs baseline: 1.0031x; 1.0031x over previous
//
#include <hip/hip_runtime.h>
#include <hip/hip_bf16.h>

#define SEQ 512
#define HID 768
#define P2  46
#define MT  64              // rows per block (4 waves x 16 rows)
#define BLK 256
#define NSTEP (HID / 32)    // 24 MFMA K-steps
#define QSTRIDE 48          // q row stride (padded, 16B-aligned)

typedef short bf16x8 __attribute__((ext_vector_type(8)));
typedef float f32x4  __attribute__((ext_vector_type(4)));

__device__ __forceinline__ unsigned short f2bf(float f) {
  union { float f; unsigned int u; } v; v.f = f;
  return (unsigned short)((v.u + 0x7FFFu + ((v.u >> 16) & 1u)) >> 16);
}

// hot-path cast: compiler lowers pairs to v_cvt_pk_bf16_f32 (RNE)
__device__ __forceinline__ short fcvt(float f) {
  __hip_bfloat16 x = __float2bfloat16(f);
  return *reinterpret_cast<short*>(&x);
}

// prep: q[b*48+p] = (h[b,i0,:]+h[b,i1,:]) . W[p,:] (exact fp32);
//       blocks with b==0 also convert W row p -> bf16 workspace
__global__ __launch_bounds__(64) void prep_kernel(
    const float* __restrict__ h, const int* __restrict__ ids,
    const float* __restrict__ W, unsigned short* __restrict__ Wb,
    float* __restrict__ q) {
  int b = blockIdx.x, p = blockIdx.y, lane = threadIdx.x;
  const float* w = W + (size_t)p * HID;
  if (b == 0) {
    #pragma unroll
    for (int j = 0; j < HID / 64; ++j)
      Wb[p * HID + lane + j * 64] = f2bf(w[lane + j * 64]);
  }
  int i0 = ids[b * 2 + 0], i1 = ids[b * 2 + 1];
  const float* r0 = h + ((size_t)b * SEQ + i0) * HID;
  const float* r1 = h + ((size_t)b * SEQ + i1) * HID;
  float acc = 0.f;
  #pragma unroll
  for (int j = 0; j < HID / 64; ++j) {
    int k = lane + j * 64;
    acc += (r0[k] + r1[k]) * w[k];
  }
  #pragma unroll
  for (int off = 32; off > 0; off >>= 1) acc += __shfl_down(acc, off, 64);
  if (lane == 0) q[b * QSTRIDE + p] = acc;
}

// main: pure stream. No LDS, no barriers. A=W (bf16, L2-resident), B=h
// (fp32 HBM -> regs, 8-deep rotated prefetch, cvt_pk to bf16), D=[p][seq].
__global__ __launch_bounds__(BLK, 2) void main_kernel(
    const float* __restrict__ h, const int* __restrict__ mask,
    const unsigned short* __restrict__ Wb, const float* __restrict__ bias,
    const float* __restrict__ q, float* __restrict__ out) {
  const int tid  = threadIdx.x;
  const int lane = tid & 63, wv = tid >> 6;
  const int mr = lane & 15, qd = lane >> 4;
  const int row0 = blockIdx.x * MT;
  const int b    = row0 >> 9;                  // SEQ = 512
  const int row  = row0 + (wv << 4) + mr;      // this lane's seq row

  const float* hb = h + (size_t)row * HID + (qd << 3);
  const unsigned short* wb = Wb + mr * HID + (qd << 3);

  // ---- prefetch: h 8-deep (2x float4/step), W 2-deep (3 frags/step) ----
  float4 ph[8][2];
  #pragma unroll
  for (int s = 0; s < 8; ++s) {
    ph[s][0] = *(const float4*)(hb + (s << 5));
    ph[s][1] = *(const float4*)(hb + (s << 5) + 4);
  }
  bf16x8 pw[2][3];
  #pragma unroll
  for (int s = 0; s < 2; ++s)
    #pragma unroll
    for (int nt = 0; nt < 3; ++nt)
      pw[s][nt] = *(const bf16x8*)(wb + nt * 16 * HID + (s << 5));

  f32x4 acc[3];
  #pragma unroll
  for (int nt = 0; nt < 3; ++nt) acc[nt] = f32x4{0.f, 0.f, 0.f, 0.f};

  // ---- 24 steps, fully unrolled, all rotation indices compile-time ----
  #pragma unroll
  for (int s = 0; s < NSTEP; ++s) {
    float4 c0 = ph[s & 7][0], c1 = ph[s & 7][1];
    if (s + 8 < NSTEP) {
      ph[s & 7][0] = *(const float4*)(hb + ((s + 8) << 5));
      ph[s & 7][1] = *(const float4*)(hb + ((s + 8) << 5) + 4);
    }
    bf16x8 hfrag = { fcvt(c0.x), fcvt(c0.y), fcvt(c0.z), fcvt(c0.w),
                     fcvt(c1.x), fcvt(c1.y), fcvt(c1.z), fcvt(c1.w) };
    bf16x8 w0 = pw[s & 1][0], w1 = pw[s & 1][1], w2 = pw[s & 1][2];
    if (s + 2 < NSTEP) {
      #pragma unroll
      for (int nt = 0; nt < 3; ++nt)
        pw[s & 1][nt] = *(const bf16x8*)(wb + nt * 16 * HID + ((s + 2) << 5));
    }
    acc[0] = __builtin_amdgcn_mfma_f32_16x16x32_bf16(w0, hfrag, acc[0], 0, 0, 0);
    acc[1] = __builtin_amdgcn_mfma_f32_16x16x32_bf16(w1, hfrag, acc[1], 0, 0, 0);
    acc[2] = __builtin_amdgcn_mfma_f32_16x16x32_bf16(w2, hfrag, acc[2], 0, 0, 0);
  }

  // ---- epilogue: D col = mr (seq row), D row = qd*4+i (p) ----
  const int mk = mask[row];
  float* orow = out + (size_t)row * P2;
  const float* qrow = q + b * QSTRIDE;
  #pragma unroll
  for (int nt = 0; nt < 3; ++nt) {
    const int p0 = (nt << 4) + (qd << 2);
    float o[4];
    #pragma unroll
    for (int i = 0; i < 4; ++i) {
      float bv = (p0 + i < P2) ? bias[p0 + i] : 0.f;
      float qv = qrow[p0 + i];                   // padded row, in-workspace
      float x = acc[nt][i] + bv + (mk ? qv : 0.f);
      float sg = 1.f / (1.f + __expf(-x));
      sg *= sg; sg *= sg;                        // sigmoid^4
      o[i] = sg;
    }
    if (p0 + 1 < P2) *(float2*)(orow + p0)     = make_float2(o[0], o[1]);
    if (p0 + 3 < P2) *(float2*)(orow + p0 + 2) = make_float2(o[2], o[3]);
  }
}

extern "C" void kernel_launch(void* const* d_in, const int* in_sizes, int n_in,
                              void* d_out, int out_size, void* d_ws, size_t ws_size,
                              hipStream_t stream) {
  const float* h    = (const float*)d_in[0];   // [64,512,768] fp32
  const int*   ids  = (const int*)d_in[1];     // [64,2]
  const int*   mask = (const int*)d_in[2];     // [64,512]
  const float* W    = (const float*)d_in[3];   // [46,768]
  const float* bias = (const float*)d_in[4];   // [46]
  float* out = (float*)d_out;                  // [64,512,46] fp32

  // workspace layout: Wb bf16 [48][768] (73728 B), then q fp32 [64][48]
  unsigned short* Wb = (unsigned short*)d_ws;
  float* q = (float*)((char*)d_ws + 48 * HID * sizeof(unsigned short));

  prep_kernel<<<dim3(64, P2), 64, 0, stream>>>(h, ids, W, Wb, q);
  main_kernel<<<dim3((64 * SEQ) / MT), BLK, 0, stream>>>(h, mask, Wb, bias, q, out);
}